// Round 1
// 331.994 us; speedup vs baseline: 1.0150x; 1.0150x over previous
//
#include <hip/hip_runtime.h>
#include <math.h>

#define SUBS 20
#define TAPS 201
#define ENO 2000
#define INO 500
#define TDATA 20000

typedef __bf16 bf16x8 __attribute__((ext_vector_type(8)));
typedef float f32x4 __attribute__((ext_vector_type(4)));

#define WGE_STRIDE 2048
#define WGI_STRIDE 512

// workspace byte offsets (ws is ~640 MB per R6 fill counter; 29.2 MB used)
#define WGE_OFF  0ull                    // ushort[64*2048] bf16 weights (E)
#define WGI_OFF  262144ull               // ushort[64*512]  bf16 weights (I)
#define KERN_OFF 327680ull               // float[40*201]   synapse kernels
#define INE_OFF  360448ull               // float[60*20000] E partial chunk0
#define INI_OFF  (INE_OFF + 4800000ull)  // float[60*20000] I (full K)
#define P1_OFF   (INI_OFF + 4800000ull)  // float[60*20000] E partial chunk1
#define P2_OFF   (P1_OFF  + 4800000ull)  // float[60*20000] E partial chunk2
#define P3_OFF   (P2_OFF  + 4800000ull)  // float[60*20000] E partial chunk3
#define SYN_OFF  (P3_OFF  + 4800000ull)  // float[60*20000] syn_in (no alias)

__device__ __forceinline__ unsigned short f2bf(float f) {
  union { float f; unsigned int u; } c; c.f = f;
  unsigned int u = c.u;
  return (unsigned short)((u + 0x7FFFu + ((u >> 16) & 1u)) >> 16);  // RTNE
}

__device__ __forceinline__ float fast_tanh(float x) {
  const float ax = fabsf(x);
  const float e  = __expf(2.f * ax);     // e=inf -> t=1 (saturation) is exact
  const float t  = 1.f - 2.f / (e + 1.f);
  return copysignf(t, x);
}

// ---------------------------------------------------------------------------
// K1: per-column prep (theta, hard/soft/softb) + kern filters + weight pads
// ---------------------------------------------------------------------------
__global__ __launch_bounds__(256) void prep_kernel(
    const float* __restrict__ u, const float* __restrict__ v,
    const float* __restrict__ C_log, const float* __restrict__ W_syn,
    const float* __restrict__ Tau_syn, const float* __restrict__ Delta_syn,
    float* __restrict__ out,
    unsigned short* __restrict__ wge, unsigned short* __restrict__ wgi,
    float* __restrict__ kern)
{
  if (blockIdx.x < 10) {
    const int n = blockIdx.x * 256 + threadIdx.x;
    if (n >= 2500) return;
    float x[SUBS], theta[SUBS], rebar[SUBS];
    float mx = -1e30f;
#pragma unroll
    for (int s = 0; s < SUBS; ++s) { x[s] = C_log[s*2500 + n]; mx = fmaxf(mx, x[s]); }
    float sum = 0.f;
#pragma unroll
    for (int s = 0; s < SUBS; ++s) { theta[s] = __expf(x[s] - mx); sum += theta[s]; }
    const float inv = 1.f / sum;
    int idx = 0; float best = -1e30f;
#pragma unroll
    for (int s = 0; s < SUBS; ++s) {
      theta[s] *= inv;
      out[60000 + s*2500 + n] = theta[s];
      const float uu = u[s*2500 + n];
      const float r = __logf(theta[s]) - __logf(-__logf(uu));
      rebar[s] = r;
      if (r > best) { best = r; idx = s; }   // first-wins strict >
    }
    const float lvk = __logf(v[idx*2500 + n]);
#pragma unroll
    for (int s = 0; s < SUBS; ++s) {
      const float hz = (s == idx) ? 1.f : 0.f;
      const float sz = 1.f / (1.f + __expf(-2.f * rebar[s])) + 1e-9f;
      const float vv = v[s*2500 + n];
      const float zb = (s == idx) ? (-__logf(-__logf(vv)))
                                  : (-__logf(-__logf(vv) / theta[s] - lvk));
      const float szb = 1.f / (1.f + __expf(-2.f * zb)) + 1e-9f;
      out[110000 + s*2500 + n] = hz;
      out[160000 + s*2500 + n] = sz;
      out[210000 + s*2500 + n] = szb;
      if (n < ENO) {
        wge[(s     )*WGE_STRIDE + n] = f2bf(hz);
        wge[(20 + s)*WGE_STRIDE + n] = f2bf(sz);
        wge[(40 + s)*WGE_STRIDE + n] = f2bf(szb);
      } else {
        const int k = n - ENO;
        wgi[(s     )*WGI_STRIDE + k] = f2bf(hz);
        wgi[(20 + s)*WGI_STRIDE + k] = f2bf(sz);
        wgi[(40 + s)*WGI_STRIDE + k] = f2bf(szb);
      }
    }
  } else {
    const int tid = threadIdx.x;
    for (int i = tid; i < 40*TAPS; i += 256) {
      const int ch = i / TAPS, m = i - ch*TAPS;
      const float dl  = __expf(Delta_syn[ch]);
      const float tau = __expf(Tau_syn[ch]);
      const float t  = fmaxf((float)m - dl, 0.f);
      const float tt = t / tau;
      kern[i] = tt * __expf(-tt) * W_syn[ch];
    }
    // zero the padded weight regions (ws is poisoned 0xAA every launch)
    for (int i = tid; i < 4*2048; i += 256) wge[(60 + (i >> 11))*WGE_STRIDE + (i & 2047)] = 0;
    for (int i = tid; i < 60*48;  i += 256) wge[(i / 48)*WGE_STRIDE + 2000 + (i % 48)] = 0;
    for (int i = tid; i < 4*512;  i += 256) wgi[(60 + (i >> 9))*WGI_STRIDE + (i & 511)] = 0;
    for (int i = tid; i < 60*12;  i += 256) wgi[(i / 12)*WGI_STRIDE + 500 + (i % 12)] = 0;
  }
}

// ---------------------------------------------------------------------------
// K2: bf16 MFMA GEMM, M=64 / BK=64 / 256 threads (4 waves), split-K E-only.
//     grid = (313, 5); y: 0..3 = E k-quarters -> {in_e,P1,P2,P3}; 4 = I full.
//     Register double-buffer: step st+1's A/B global loads are issued BEFORE
//     step st's convert+stage, so the compiler emits a counted vmcnt wait and
//     the loads stay in flight across both barriers + the MFMA phase.
//     M=64/256t gives ~6 resident WGs/CU (vs 3 at M=128/512t) for cross-WG
//     latency hiding on top of the intra-wave prefetch.
// ---------------------------------------------------------------------------
#define LOAD_A(k0, d0, d1, d2, d3) do {                          \
    const int kb_ = (k0) + slotA*16;                             \
    const int c0_ = (kb_ +  4 <= K) ? kb_      : K - 4;          \
    const int c1_ = (kb_ +  8 <= K) ? kb_ +  4 : K - 4;          \
    const int c2_ = (kb_ + 12 <= K) ? kb_ +  8 : K - 4;          \
    const int c3_ = (kb_ + 16 <= K) ? kb_ + 12 : K - 4;          \
    d0 = *(const float4*)(Arow + c0_);                           \
    d1 = *(const float4*)(Arow + c1_);                           \
    d2 = *(const float4*)(Arow + c2_);                           \
    d3 = *(const float4*)(Arow + c3_);                           \
  } while (0)

__global__ __launch_bounds__(256) void gemm_kernel(
    const float* __restrict__ S_e, const float* __restrict__ S_i,
    const unsigned short* __restrict__ wge, const unsigned short* __restrict__ wgi,
    float* __restrict__ in_e, float* __restrict__ in_i,
    float* __restrict__ P1, float* __restrict__ P2, float* __restrict__ P3)
{
  __shared__ unsigned short Alds[64*72];   // [t-row][k] bf16, stride 72
  __shared__ unsigned short Blds[64*72];   // [c-row][k] bf16, stride 72
  const int tid  = threadIdx.x;
  const int wave = tid >> 6;
  const int lane = tid & 63;
  const int m16  = lane & 15;
  const int quad = lane >> 4;
  const int t0   = blockIdx.x * 64;
  const int cy   = blockIdx.y;
  const bool isE = (cy < 4);

  const float* S = isE ? S_e : S_i;
  const unsigned short* Wg = isE ? wge : wgi;
  float* outp = (cy == 0) ? in_e : (cy == 1) ? P1 : (cy == 2) ? P2
              : (cy == 3) ? P3   : in_i;
  const int K       = isE ? ENO : INO;
  const int Wstride = isE ? WGE_STRIDE : WGI_STRIDE;
  const int k_base  = isE ? cy * 512 : 0;

  // staging maps: 4 threads per row, 16 elems (A: floats, B: shorts) each
  const int rowA  = tid >> 2;          // 0..63
  const int slotA = tid & 3;
  const int tA    = t0 + rowA;
  const float* Arow = S + (size_t)((tA < TDATA) ? tA : TDATA - 1) * K;
  const unsigned short* Brow = Wg + (size_t)rowA * Wstride + slotA*16;

  f32x4 acc0 = {0.f,0.f,0.f,0.f};
  f32x4 acc1 = acc0, acc2 = acc0, acc3 = acc0;

  // prologue: issue step-0 loads
  float4 a0, a1, a2, a3, n0, n1, n2, n3;
  uint4 bw0, bw1, nb0, nb1;
  {
    const int k0 = k_base;
    bw0 = *(const uint4*)(Brow + k0);
    bw1 = *(const uint4*)(Brow + k0 + 8);
    LOAD_A(k0, a0, a1, a2, a3);
  }

#pragma unroll
  for (int st = 0; st < 8; ++st) {
    // issue next-step loads first: independent of current regs, so they fly
    // during convert + barriers + MFMA (no global_load_lds -> no vmcnt(0)
    // drain at the barrier; these are wave-private register loads)
    if (st < 7) {
      const int kn = k_base + (st + 1) * 64;
      nb0 = *(const uint4*)(Brow + kn);
      nb1 = *(const uint4*)(Brow + kn + 8);
      LOAD_A(kn, n0, n1, n2, n3);
    }
    // convert current A regs -> bf16 and stage both tiles
    ushort4 p0, p1, p2, p3;
    p0.x = f2bf(a0.x); p0.y = f2bf(a0.y); p0.z = f2bf(a0.z); p0.w = f2bf(a0.w);
    p1.x = f2bf(a1.x); p1.y = f2bf(a1.y); p1.z = f2bf(a1.z); p1.w = f2bf(a1.w);
    p2.x = f2bf(a2.x); p2.y = f2bf(a2.y); p2.z = f2bf(a2.z); p2.w = f2bf(a2.w);
    p3.x = f2bf(a3.x); p3.y = f2bf(a3.y); p3.z = f2bf(a3.z); p3.w = f2bf(a3.w);
    unsigned short* adst = &Alds[rowA*72 + slotA*16];
    *(ushort4*)(adst    ) = p0;  *(ushort4*)(adst + 4) = p1;
    *(ushort4*)(adst + 8) = p2;  *(ushort4*)(adst +12) = p3;
    unsigned short* bdst = &Blds[rowA*72 + slotA*16];
    *(uint4*)(bdst    ) = bw0;
    *(uint4*)(bdst + 8) = bw1;
    __syncthreads();
    // compute: 2 k-halves of 32; frag A[m=lane&15][k=quad*8+j]
#pragma unroll
    for (int h = 0; h < 2; ++h) {
      const int kh = h*32 + quad*8;
      const bf16x8 a  = *(const bf16x8*)(&Alds[(wave*16 + m16)*72 + kh]);
      const bf16x8 b0 = *(const bf16x8*)(&Blds[(      m16)*72 + kh]);
      const bf16x8 b1 = *(const bf16x8*)(&Blds[(16 + m16)*72 + kh]);
      const bf16x8 b2 = *(const bf16x8*)(&Blds[(32 + m16)*72 + kh]);
      const bf16x8 b3 = *(const bf16x8*)(&Blds[(48 + m16)*72 + kh]);
      acc0 = __builtin_amdgcn_mfma_f32_16x16x32_bf16(a, b0, acc0, 0, 0, 0);
      acc1 = __builtin_amdgcn_mfma_f32_16x16x32_bf16(a, b1, acc1, 0, 0, 0);
      acc2 = __builtin_amdgcn_mfma_f32_16x16x32_bf16(a, b2, acc2, 0, 0, 0);
      acc3 = __builtin_amdgcn_mfma_f32_16x16x32_bf16(a, b3, acc3, 0, 0, 0);
    }
    __syncthreads();
    // rotate buffers (SSA renames, no runtime indexing)
    a0 = n0; a1 = n1; a2 = n2; a3 = n3;
    bw0 = nb0; bw1 = nb1;
  }
  // epilogue: C/D layout col=m16 -> c, row=quad*4+r -> t-local (within wave's 16)
  const int t = t0 + wave*16 + quad*4;
  if (t < TDATA) {
    float* o = outp + t;
    *(float4*)(o + (size_t)(     m16)*TDATA) = *(float4*)&acc0;
    *(float4*)(o + (size_t)(16 + m16)*TDATA) = *(float4*)&acc1;
    *(float4*)(o + (size_t)(32 + m16)*TDATA) = *(float4*)&acc2;
    if (m16 < 12)
      *(float4*)(o + (size_t)(48 + m16)*TDATA) = *(float4*)&acc3;
  }
}

// ---------------------------------------------------------------------------
// K3: 201-tap causal FIR per (var,s), with the split-K reduction fused into
//     the LDS staging: E window = in_e + P1 + P2 + P3, I window = in_i.
// ---------------------------------------------------------------------------
__device__ __forceinline__ int swz(int i) { return i + (i >> 5); }

__global__ __launch_bounds__(256) void conv_kernel(
    const float* __restrict__ in_e, const float* __restrict__ P1,
    const float* __restrict__ P2,  const float* __restrict__ P3,
    const float* __restrict__ in_i,
    const float* __restrict__ kern, float* __restrict__ syn)
{
  __shared__ float Ee[2320];
  __shared__ float Ei[2320];
  const int ch = blockIdx.y;            // var*20 + s
  const int t0 = blockIdx.x * 2048;
  const int s  = ch % SUBS;
  const size_t off = (size_t)ch * TDATA;
  for (int i = threadIdx.x; i < 2248; i += 256) {
    const int g = t0 - 200 + i;
    float e = 0.f, ii = 0.f;
    if (g >= 0 && g < TDATA) {
      e = in_e[off + g] + P1[off + g] + P2[off + g] + P3[off + g];
      ii = in_i[off + g];
    }
    Ee[swz(i)] = e;
    Ei[swz(i)] = ii;
  }
  __syncthreads();
  const float* ke = kern + (size_t)(s*2    ) * TAPS;
  const float* ki = kern + (size_t)(s*2 + 1) * TAPS;
  const int tb = threadIdx.x * 8;
  float acc[8] = {0.f,0.f,0.f,0.f,0.f,0.f,0.f,0.f};
  float we[8], wi[8];
#pragma unroll
  for (int j = 0; j < 8; ++j) {
    we[j] = Ee[swz(tb + 200 + j)];
    wi[j] = Ei[swz(tb + 200 + j)];
  }
#pragma unroll 8
  for (int m = 0; m < TAPS; ++m) {
    const float k0 = ke[m];
    const float k1 = ki[m];
#pragma unroll
    for (int j = 0; j < 8; ++j)
      acc[j] = fmaf(we[j], k0, fmaf(wi[j], k1, acc[j]));
    if (m < TAPS - 1) {
#pragma unroll
      for (int j = 7; j > 0; --j) { we[j] = we[j-1]; wi[j] = wi[j-1]; }
      we[0] = Ee[swz(tb + 199 - m)];
      wi[0] = Ei[swz(tb + 199 - m)];
    }
  }
  const int t = t0 + tb;
  if (t < TDATA) {
    float* o = syn + off + t;
    *(float4*)(o    ) = make_float4(acc[0], acc[1], acc[2], acc[3]);
    *(float4*)(o + 4) = make_float4(acc[4], acc[5], acc[6], acc[7]);
  }
}

// ---------------------------------------------------------------------------
// K4: tanh tree combine -> V outputs
// ---------------------------------------------------------------------------
__global__ __launch_bounds__(256) void tree_kernel(
    const float* __restrict__ syn, const float* __restrict__ W_sub,
    const float* __restrict__ V_o, float* __restrict__ out)
{
  const int t = blockIdx.x * 256 + threadIdx.x;
  const int var = blockIdx.y;
  if (t >= TDATA) return;
  const float* sp = syn + (size_t)var * SUBS * TDATA + t;
  float so[SUBS];
#pragma unroll
  for (int s = SUBS - 1; s >= 0; --s) {
    float val = sp[(size_t)s * TDATA];
    const int c1 = 2*s + 1, c2 = 2*s + 2;
    if (c1 < SUBS) val += so[c1] * W_sub[c1];
    if (c2 < SUBS) val += so[c2] * W_sub[c2];
    so[s] = fast_tanh(val);
  }
  out[(size_t)var * TDATA + t] = so[0] * W_sub[0] + V_o[0];
}

extern "C" void kernel_launch(void* const* d_in, const int* in_sizes, int n_in,
                              void* d_out, int out_size, void* d_ws, size_t ws_size,
                              hipStream_t stream) {
  const float* S_e     = (const float*)d_in[0];
  const float* S_i     = (const float*)d_in[1];
  const float* u       = (const float*)d_in[2];
  const float* v       = (const float*)d_in[3];
  const float* W_syn   = (const float*)d_in[4];
  const float* Tau_syn = (const float*)d_in[5];
  const float* Delta   = (const float*)d_in[6];
  const float* W_sub   = (const float*)d_in[7];
  const float* V_o     = (const float*)d_in[8];
  const float* C_log   = (const float*)d_in[10];   // d_in[9] = Theta, unused
  float* out = (float*)d_out;
  char* ws = (char*)d_ws;
  unsigned short* wge = (unsigned short*)(ws + WGE_OFF);
  unsigned short* wgi = (unsigned short*)(ws + WGI_OFF);
  float* kern = (float*)(ws + KERN_OFF);
  float* in_e = (float*)(ws + INE_OFF);
  float* in_i = (float*)(ws + INI_OFF);
  float* P1   = (float*)(ws + P1_OFF);
  float* P2   = (float*)(ws + P2_OFF);
  float* P3   = (float*)(ws + P3_OFF);
  float* syn  = (float*)(ws + SYN_OFF);

  prep_kernel<<<dim3(11), dim3(256), 0, stream>>>(u, v, C_log, W_syn, Tau_syn,
                                                  Delta, out, wge, wgi, kern);
  gemm_kernel<<<dim3(313, 5), dim3(256), 0, stream>>>(
      S_e, S_i, wge, wgi, in_e, in_i, P1, P2, P3);
  conv_kernel<<<dim3(10, 60), dim3(256), 0, stream>>>(in_e, P1, P2, P3, in_i,
                                                      kern, syn);
  tree_kernel<<<dim3(79, 3), dim3(256), 0, stream>>>(syn, W_sub, V_o, out);
}